// Round 6
// baseline (1809.688 us; speedup 1.0000x reference)
//
#include <hip/hip_runtime.h>
#include <cstdint>

static constexpr int B   = 8;
static constexpr int N0  = 4096;
static constexpr int NQ  = 1024;
static constexpr int KNB = 16;

// ---------------------------------------------------------------------------
// u64 wave max; result valid in LANE 63 only. No readlane/ballot — pure VALU.
// ---------------------------------------------------------------------------
__device__ __forceinline__ unsigned long long wave_max_u64_l63(unsigned long long k) {
#define STEPU_(ctrl)                                                                    \
  {                                                                                     \
    unsigned lo_ = (unsigned)k, hi_ = (unsigned)(k >> 32);                              \
    unsigned plo_ = (unsigned)__builtin_amdgcn_update_dpp((int)lo_, (int)lo_, ctrl,     \
                                                          0xf, 0xf, false);             \
    unsigned phi_ = (unsigned)__builtin_amdgcn_update_dpp((int)hi_, (int)hi_, ctrl,     \
                                                          0xf, 0xf, false);             \
    unsigned long long pk_ = ((unsigned long long)phi_ << 32) | plo_;                   \
    if (pk_ > k) k = pk_;                                                               \
  }
  STEPU_(0x111) STEPU_(0x112) STEPU_(0x114) STEPU_(0x118) STEPU_(0x142) STEPU_(0x143)
#undef STEPU_
  return k;
}

// ---------------------------------------------------------------------------
// prep: split x; write packed c4 = {x,y,z,|c|^2}, normal, plane, f0
// ---------------------------------------------------------------------------
__global__ void prep_kernel(const float* __restrict__ x,
                            const float* __restrict__ W_in,
                            const float* __restrict__ b_in,
                            float4* __restrict__ c4, float* __restrict__ nrm,
                            float* __restrict__ pl, float* __restrict__ f0) {
  int i = blockIdx.x * 256 + threadIdx.x;
  if (i >= B * N0) return;
  const float* xp = x + (size_t)i * 7;
  float cx = xp[0], cy = xp[1], cz = xp[2];
  // tie-sensitive (feeds kNN distance): exact fp32, ref association order
  float kk = __fadd_rn(__fadd_rn(__fmul_rn(cx, cx), __fmul_rn(cy, cy)), __fmul_rn(cz, cz));
  c4[i] = make_float4(cx, cy, cz, kk);
  nrm[i * 3 + 0] = xp[3]; nrm[i * 3 + 1] = xp[4]; nrm[i * 3 + 2] = xp[5];
  pl[i] = xp[6];
#pragma unroll
  for (int o = 0; o < 8; o++) {
    f0[(size_t)i * 8 + o] = cx * W_in[o * 3 + 0] + cy * W_in[o * 3 + 1] + cz * W_in[o * 3 + 2] + b_in[o];
  }
}

// ---------------------------------------------------------------------------
// kNN body: STREAMING INSERTION TOP-K (harness-verified R1). Wave per query.
// ---------------------------------------------------------------------------
template <int NC>
__device__ __forceinline__ void knn_body(int bq, int lane,
                                         const float4* __restrict__ q4,
                                         const float4* __restrict__ k4,
                                         int Q, int Nk, int* __restrict__ out) {
  int b = bq / Q;
  float4 q = q4[bq];
  const float4* kb = k4 + (size_t)b * Nk + lane;
  const float INF    = __int_as_float(0x7f800000);
  const float NEGINF = __int_as_float(0xff800000);
  float myd = INF;  // sorted list value (replicated per 16-lane row)
  int   myi = 0;
  float kth = INF;  // current 16th-smallest (wave-uniform scalar)
  const bool isl0 = (lane & 15) == 0;
  constexpr int G = (NC >= 8) ? 8 : NC;  // load-batching group
  for (int c0 = 0; c0 < NC; c0 += G) {
    float dg[G];
#pragma unroll
    for (int u = 0; u < G; u++) {
      float4 kp = kb[(c0 + u) * 64];
      float dot = __fadd_rn(__fadd_rn(__fmul_rn(q.x, kp.x), __fmul_rn(q.y, kp.y)),
                            __fmul_rn(q.z, kp.z));
      dg[u] = __fadd_rn(__fsub_rn(q.w, __fmul_rn(2.0f, dot)), kp.w);
    }
#pragma unroll
    for (int u = 0; u < G; u++) {
      float d = dg[u];
      unsigned long long m = __ballot(d < kth);
      while (m) {
        int j = __builtin_ctzll(m);  // wave-uniform (scalar)
        float dv = __int_as_float(__builtin_amdgcn_readlane(__float_as_int(d), j));
        int   iv = (c0 + u) * 64 + j;
        // insert (dv, iv): shift-down all positions with value > dv
        bool gt = (myd > dv);
        float pd = __int_as_float(__builtin_amdgcn_update_dpp(
            0, __float_as_int(myd), 0x111, 0xf, 0xf, true));
        int   pi = __builtin_amdgcn_update_dpp(0, myi, 0x111, 0xf, 0xf, true);
        pd = isl0 ? NEGINF : pd;  // position 0 always takes dv when it shifts
        bool tp = (pd > dv);
        float nd = tp ? pd : dv;
        int   ni = tp ? pi : iv;
        myd = gt ? nd : myd;
        myi = gt ? ni : myi;
        kth = __int_as_float(__builtin_amdgcn_readlane(__float_as_int(myd), 15));
        m = __ballot(d < kth);  // kth only shrinks -> lanes may drop out
        m = (j < 63) ? (m & (~0ull << (j + 1))) : 0ull;  // only lanes > j remain
      }
    }
  }
  if (lane < KNB) out[(size_t)bq * KNB + lane] = myi;
}

// ---------------------------------------------------------------------------
// ctrY body: ctrY[b,q,o] = sum_c fq_row[c] * W[o, CF+c]; optional ridx.
// ---------------------------------------------------------------------------
template <int CF, int CO>
__device__ __forceinline__ void ctry_body(int i, int total, const float* __restrict__ fq,
                                          const float* __restrict__ W,
                                          float* __restrict__ ctrY,
                                          const int* __restrict__ ridx, int Q, int Nsrc) {
  if (i >= total) return;
  int o = i % CO, bq = i / CO;
  const float* fp;
  if (ridx) {
    int b = bq / Q;
    fp = fq + ((size_t)b * Nsrc + ridx[bq]) * CF;
  } else {
    fp = fq + (size_t)bq * CF;
  }
  const float* wp = W + (size_t)o * (2 * CF) + CF;
  float acc = 0.f;
#pragma unroll
  for (int c = 0; c < CF; c++) acc = fmaf(fp[c], wp[c], acc);
  ctrY[i] = acc;
}

// ---------------------------------------------------------------------------
// FPS v5 (harness-verified R1): BLK=256 (4 waves), one block per batch.
// key k=(dist_bits<<12)|(4095-bi) DPP-u64-maxed; lane 63 writes wave slot;
// ONE barrier; cross-wave reduce = 2x ds_read_b128 broadcast + 3 u64 maxes;
// winner coords via same-address (broadcast) LDS reads sxy[win]/sz[win].
// u64 max == (max dist, tie -> min index) == jnp.argmax first-occurrence.
// ---------------------------------------------------------------------------
template <int NPTS>
__device__ __forceinline__ void fps_body(const float4* __restrict__ cb, int* w) {
  constexpr int BLK = 256;
  constexpr int M = NPTS / BLK;
  constexpr int NW = BLK / 64;  // 4
  __shared__ __align__(16) float2 sxy[NPTS];
  __shared__ float szz[NPTS];
  __shared__ __align__(16) unsigned long long skey[2][NW];
  const int tid = threadIdx.x;
  const int wid = tid >> 6, lane = tid & 63;
  float cx[M], cy[M], cz[M], dist[M];
#pragma unroll
  for (int i = 0; i < M; i++) {
    float4 p = cb[tid * M + i];
    cx[i] = p.x; cy[i] = p.y; cz[i] = p.z;
    dist[i] = 3.4e38f;
    sxy[tid * M + i] = make_float2(p.x, p.y);
    szz[tid * M + i] = p.z;
  }
  w[0] = w[1] = w[2] = w[3] = 0;
  float4 p0 = cb[0];
  float px = p0.x, py = p0.y, pz = p0.z;
  __syncthreads();
  for (int t = 1; t < NQ; t++) {
    float bv = -1.f; int bi = 0;
#pragma unroll
    for (int i = 0; i < M; i++) {
      float dx = __fsub_rn(cx[i], px), dy = __fsub_rn(cy[i], py), dz = __fsub_rn(cz[i], pz);
      float d = __fadd_rn(__fadd_rn(__fmul_rn(dx, dx), __fmul_rn(dy, dy)), __fmul_rn(dz, dz));
      float dd = dist[i]; dd = (d < dd) ? d : dd; dist[i] = dd;
      if (dd > bv) { bv = dd; bi = tid * M + i; }
    }
    unsigned long long k =
        ((unsigned long long)__float_as_uint(bv) << 12) | (unsigned)(4095 - bi);
    k = wave_max_u64_l63(k);
    int p = t & 1;
    if (lane == 63) skey[p][wid] = k;
    __syncthreads();
    ulonglong2 ab = *(const ulonglong2*)&skey[p][0];
    ulonglong2 cd = *(const ulonglong2*)&skey[p][2];
    unsigned long long m0 = (ab.x > ab.y) ? ab.x : ab.y;
    unsigned long long m1 = (cd.x > cd.y) ? cd.x : cd.y;
    unsigned long long mk = (m0 > m1) ? m0 : m1;
    int win = 4095 - (int)(mk & 0xFFFull);
    float2 pxy = sxy[win];
    px = pxy.x; py = pxy.y; pz = szz[win];
    if (t == tid) w[0] = win;
    if (t == tid + 256) w[1] = win;
    if (t == tid + 512) w[2] = win;
    if (t == tid + 768) w[3] = win;
  }
}

// ---------------------------------------------------------------------------
// FPS v10: SINGLE-WAVE fps for NPTS=1024 (M=16/lane), register-only reduce.
// Per-lane scan tracks (bv, bi, bx, by, bz); coord cndmasks hang OFF the vcc
// chain (only bv feeds the next compare). Wave phase: 6 fused DPP v_max_f32
// (lane 63 valid) -> readlane -> ballot(bv==wmax) -> ctz -> owner lane L ->
// 4 readlanes (win, x, y, z). No LDS on the serial path. Selection ==
// (max dist, tie -> min lane, tie -> min i) == min global index among maxima
// (lane-major point assignment) == jnp.argmax first-occurrence — identical
// to the harness-verified v5 key scheme. Winners stream to swin (lane-0
// ds_write, never waited on in-loop).
// ---------------------------------------------------------------------------
template <int NPTS>
__device__ __forceinline__ void fps1w_body(const float4* __restrict__ cb,
                                           int* __restrict__ swin) {
  constexpr int M = NPTS / 64;
  const int lane = threadIdx.x;  // caller guarantees threadIdx.x < 64
  float cx[M], cy[M], cz[M], dist[M];
#pragma unroll
  for (int i = 0; i < M; i++) {
    float4 p = cb[lane * M + i];
    cx[i] = p.x; cy[i] = p.y; cz[i] = p.z;
    dist[i] = 3.4e38f;
  }
  float4 p0 = cb[0];
  float px = p0.x, py = p0.y, pz = p0.z;
  for (int t = 1; t < NQ; t++) {
    float bv = -1.f; int bi = 0;
    float bx = px, by = py, bz = pz;  // dd >= 0 > -1 so always overwritten
#pragma unroll
    for (int i = 0; i < M; i++) {
      float dx = __fsub_rn(cx[i], px), dy = __fsub_rn(cy[i], py), dz = __fsub_rn(cz[i], pz);
      float d = __fadd_rn(__fadd_rn(__fmul_rn(dx, dx), __fmul_rn(dy, dy)), __fmul_rn(dz, dz));
      float dd = dist[i]; dd = (d < dd) ? d : dd; dist[i] = dd;
      if (dd > bv) { bv = dd; bi = lane * M + i; bx = cx[i]; by = cy[i]; bz = cz[i]; }
    }
    float wm = bv;
#define SMAX_(ctrl)                                                                     \
  {                                                                                     \
    int t_ = __builtin_amdgcn_update_dpp(__float_as_int(wm), __float_as_int(wm), ctrl,  \
                                         0xf, 0xf, false);                              \
    wm = fmaxf(wm, __int_as_float(t_));                                                 \
  }
    SMAX_(0x111) SMAX_(0x112) SMAX_(0x114) SMAX_(0x118) SMAX_(0x142) SMAX_(0x143)
#undef SMAX_
    float wmax = __int_as_float(__builtin_amdgcn_readlane(__float_as_int(wm), 63));
    unsigned long long tied = __ballot(bv == wmax);
    int L = (int)__builtin_ctzll(tied);  // min lane == min global index
    int win = __builtin_amdgcn_readlane(bi, L);
    px = __int_as_float(__builtin_amdgcn_readlane(__float_as_int(bx), L));
    py = __int_as_float(__builtin_amdgcn_readlane(__float_as_int(by), L));
    pz = __int_as_float(__builtin_amdgcn_readlane(__float_as_int(bz), L));
    if (lane == 0) swin[t] = win;
  }
}

// ---------------------------------------------------------------------------
// edge-conv pass A body (NT threads): wave per (b,q); lane = g*16+k.
// ---------------------------------------------------------------------------
template <int CF, int CO, int NT>
__device__ __forceinline__ void edgeconv_body(
    int blkid, const float* __restrict__ fq, const float* __restrict__ fk,
    const int* __restrict__ knn, const float* __restrict__ Wfull,
    const float* __restrict__ ctrY, const int* __restrict__ ridx,
    float* __restrict__ ymin, float* __restrict__ ymax,
    float* __restrict__ gstats, int Q, int Nk) {
  constexpr int J = CO / 4;
  constexpr int SEC = J * CF + 8;
  constexpr int NWARP = NT / 64;
  __shared__ float Wl[4 * SEC];
  __shared__ float sstat[8];
  for (int t = threadIdx.x; t < CO * CF; t += NT) {
    int o = t / CF, c = t % CF;
    Wl[(o / J) * SEC + (o % J) * CF + c] = Wfull[(size_t)o * (2 * CF) + c];
  }
  if (threadIdx.x < 8) sstat[threadIdx.x] = 0.0f;
  __syncthreads();
  const int wid = threadIdx.x >> 6, lane = threadIdx.x & 63;
  const int bq = blkid * NWARP + wid;
  const int b = bq / Q;
  const int g = lane >> 4, k = lane & 15;
  const int ni = knn[(size_t)bq * KNB + k];
  const float* nbp = fk + (size_t)(b * Nk + ni) * CF;
  const float* cp = ridx ? fq + ((size_t)b * Nk + ridx[bq]) * CF
                         : fq + (size_t)bq * CF;
  float acc[J];
#pragma unroll
  for (int j = 0; j < J; j++) acc[j] = 0.0f;
  const float* wg = &Wl[g * SEC];
#pragma unroll
  for (int c = 0; c < CF; c += 4) {
    float4 nb4 = *(const float4*)(nbp + c);
    float4 c4  = *(const float4*)(cp + c);
    float e0 = nb4.x - c4.x, e1 = nb4.y - c4.y, e2 = nb4.z - c4.z, e3 = nb4.w - c4.w;
#pragma unroll
    for (int j = 0; j < J; j++) {
      float4 w4 = *(const float4*)(wg + j * CF + c);
      acc[j] = fmaf(e0, w4.x, acc[j]);
      acc[j] = fmaf(e1, w4.y, acc[j]);
      acc[j] = fmaf(e2, w4.z, acc[j]);
      acc[j] = fmaf(e3, w4.w, acc[j]);
    }
  }
  float s = 0.f, s2 = 0.f;
  const float* cyp = ctrY + (size_t)bq * CO + g * J;
#pragma unroll
  for (int j = 0; j < J; j++) {
    float y = acc[j] + cyp[j];
    acc[j] = y;            // acc becomes running max
    s += y; s2 = fmaf(y, y, s2);
  }
  float mn[J];
#pragma unroll
  for (int j = 0; j < J; j++) mn[j] = acc[j];
#pragma unroll
  for (int m = 1; m < 16; m <<= 1) {  // reduce over the 16 k-lanes
#pragma unroll
    for (int j = 0; j < J; j++) {
      float a = __shfl_xor(acc[j], m); if (a > acc[j]) acc[j] = a;
      float c2 = __shfl_xor(mn[j], m); if (c2 < mn[j]) mn[j] = c2;
    }
    s  += __shfl_xor(s, m);
    s2 += __shfl_xor(s2, m);
  }
  if (k == 0) {
    float* mnp = ymin + (size_t)bq * CO + g * J;
    float* mxp = ymax + (size_t)bq * CO + g * J;
#pragma unroll
    for (int j = 0; j < J; j++) { mnp[j] = mn[j]; mxp[j] = acc[j]; }
    atomicAdd(&sstat[g], s);
    atomicAdd(&sstat[4 + g], s2);
  }
  __syncthreads();
  if (threadIdx.x < 8) atomicAdd(&gstats[b * 8 + threadIdx.x], sstat[threadIdx.x]);
}

// ---------------------------------------------------------------------------
// mega1 (256 thr): blocks [0,8) fps1 v5 (+ gather tail); [8,8+8192) knn1;
// rest ctry1. All roles depend only on prep outputs.
// ---------------------------------------------------------------------------
__global__ __launch_bounds__(256, 2) void mega1_kernel(
    const float4* __restrict__ c40, const float* __restrict__ nrm,
    const float* __restrict__ pl, const float* __restrict__ f0,
    const float* __restrict__ W1, int* __restrict__ idx1,
    float4* __restrict__ c4q1, float* __restrict__ nq1, float* __restrict__ pq1,
    int* __restrict__ knn1, float* __restrict__ ctrY1) {
  int blk = blockIdx.x;
  if (blk < 8) {
    const int b = blk, tid = threadIdx.x;
    const float4* cb = c40 + (size_t)b * N0;
    int w[4];
    fps_body<N0>(cb, w);
    int* idxb = idx1 + (size_t)b * NQ;
#pragma unroll
    for (int u = 0; u < 4; u++) {
      int r = tid + u * 256;
      int s = (u == 0 && tid == 0) ? 0 : w[u];
      idxb[r] = s;
      c4q1[(size_t)b * NQ + r] = cb[s];
      const float* np = nrm + ((size_t)b * N0 + s) * 3;
      float* ndp = nq1 + ((size_t)b * NQ + r) * 3;
      ndp[0] = np[0]; ndp[1] = np[1]; ndp[2] = np[2];
      pq1[(size_t)b * NQ + r] = pl[(size_t)b * N0 + s];
    }
  } else if (blk < 8 + 8192) {
    int bq = (blk - 8) * 4 + (threadIdx.x >> 6);
    knn_body<64>(bq, threadIdx.x & 63, c40, c40, N0, N0, knn1);
  } else {
    int i = (blk - (8 + 8192)) * 256 + threadIdx.x;
    ctry_body<8, 32>(i, B * N0 * 32, f0, W1, ctrY1, nullptr, 0, 0);
  }
}

// ---------------------------------------------------------------------------
// ec1f (256 thr): blocks [0,8) fps2 v10 (+ gather tail -> idx2, c4q2, d_out
// coords/normal/plane); [8,8200) edgeconv layer 1; [8200,10248) knn2 ->
// knnC (fresh buffer: knnA still being read by ec1); [10248,12296) knn3 ->
// knnB. All roles depend only on mega1 outputs; fps2/knn2/knn3 hide under
// edgeconv1's blocks.
// ---------------------------------------------------------------------------
__global__ __launch_bounds__(256, 2) void ec1f_kernel(
    const float4* __restrict__ c40, const float4* __restrict__ c4q1,
    const float* __restrict__ nq1, const float* __restrict__ pq1,
    const float* __restrict__ f0, const int* __restrict__ knn1,
    const float* __restrict__ W1, const float* __restrict__ ctrY1,
    float* __restrict__ ymin, float* __restrict__ ymax, float* __restrict__ gst1,
    int* __restrict__ idx2, float4* __restrict__ c4q2,
    float* __restrict__ cq2out, float* __restrict__ nq2out,
    float* __restrict__ pq2out, int* __restrict__ knnC, int* __restrict__ knnB) {
  int blk = blockIdx.x;
  if (blk < 8) {
    if (threadIdx.x < 64) {
      __shared__ int swin2[NQ];
      const int b = blk, lane = threadIdx.x;
      const float4* cqb = c4q1 + (size_t)b * NQ;
      fps1w_body<NQ>(cqb, swin2);
      int* idxb = idx2 + (size_t)b * NQ;
#pragma unroll
      for (int u = 0; u < NQ / 64; u++) {
        int r = lane + u * 64;
        int s = (r == 0) ? 0 : swin2[r];
        idxb[r] = s;
        float4 c = cqb[s];
        c4q2[(size_t)b * NQ + r] = c;
        float* cd = cq2out + ((size_t)b * NQ + r) * 3;
        cd[0] = c.x; cd[1] = c.y; cd[2] = c.z;
        const float* np = nq1 + ((size_t)b * NQ + s) * 3;
        float* ndp = nq2out + ((size_t)b * NQ + r) * 3;
        ndp[0] = np[0]; ndp[1] = np[1]; ndp[2] = np[2];
        pq2out[(size_t)b * NQ + r] = pq1[(size_t)b * NQ + s];
      }
    }
  } else if (blk < 8 + 8192) {
    edgeconv_body<8, 32, 256>(blk - 8, f0, f0, knn1, W1, ctrY1, nullptr,
                              ymin, ymax, gst1, N0, N0);
  } else if (blk < 8 + 8192 + 2048) {
    int bq = (blk - (8 + 8192)) * 4 + (threadIdx.x >> 6);
    knn_body<64>(bq, threadIdx.x & 63, c4q1, c40, NQ, N0, knnC);
  } else {
    int bq = (blk - (8 + 8192 + 2048)) * 4 + (threadIdx.x >> 6);
    knn_body<16>(bq, threadIdx.x & 63, c4q1, c4q1, NQ, NQ, knnB);
  }
}

// ---------------------------------------------------------------------------
// mega3 (256 thr): [0,2048) knn4 (c4q2 vs c4q1); rest ctry4 (f3 via idx2).
// knnB safe to overwrite: ec3 consumed knn3 already.
// ---------------------------------------------------------------------------
__global__ __launch_bounds__(256, 4) void mega3_kernel(
    const float4* __restrict__ c4q1, const float4* __restrict__ c4q2,
    const float* __restrict__ f3, const int* __restrict__ idx2,
    const float* __restrict__ W4, int* __restrict__ knn4, float* __restrict__ ctrY4) {
  int blk = blockIdx.x;
  if (blk < 2048) {
    int bq = blk * 4 + (threadIdx.x >> 6);
    knn_body<16>(bq, threadIdx.x & 63, c4q2, c4q1, NQ, NQ, knn4);
  } else {
    int i = (blk - 2048) * 256 + threadIdx.x;
    ctry_body<64, 128>(i, B * NQ * 128, f3, W4, ctrY4, idx2, NQ, NQ);
  }
}

// ---------------------------------------------------------------------------
// standalone ctry (layers 2 & 3; optional ridx)
// ---------------------------------------------------------------------------
template <int CF, int CO>
__global__ void ctry_kernel(const float* __restrict__ fq, const float* __restrict__ W,
                            float* __restrict__ ctrY, int total,
                            const int* __restrict__ ridx, int Q, int Nsrc) {
  int i = blockIdx.x * 256 + threadIdx.x;
  ctry_body<CF, CO>(i, total, fq, W, ctrY, ridx, Q, Nsrc);
}

// ---------------------------------------------------------------------------
// standalone edgeconv (layers 2,3,4) — 256 thr
// ---------------------------------------------------------------------------
template <int CF, int CO>
__global__ __launch_bounds__(256) void edgeconv_kernel(
    const float* __restrict__ fq, const float* __restrict__ fk,
    const int* __restrict__ knn, const float* __restrict__ Wfull,
    const float* __restrict__ ctrY, const int* __restrict__ ridx,
    float* __restrict__ ymin, float* __restrict__ ymax,
    float* __restrict__ gstats, int Q, int Nk) {
  edgeconv_body<CF, CO, 256>(blockIdx.x, fq, fk, knn, Wfull, ctrY, ridx,
                             ymin, ymax, gstats, Q, Nk);
}

// ---------------------------------------------------------------------------
// pass B (gn_final fused): f = lrelu((sel - m)*gw*rs + gb),
// sel = max over K if scale>=0 else min (monotone-commute, exact).
// ---------------------------------------------------------------------------
template <int CO>
__global__ void gn_out_kernel(const float* __restrict__ ymin, const float* __restrict__ ymax,
                              const float* __restrict__ gstats, const float* __restrict__ gw,
                              const float* __restrict__ gb, float* __restrict__ fout,
                              int total, int Q, float inv_cnt) {
  int i = blockIdx.x * 256 + threadIdx.x;
  if (i >= total) return;
  constexpr int J = CO / 4;
  int o = i % CO; int bq = i / CO; int b = bq / Q;
  int g = o / J;
  float m  = gstats[b * 8 + g] * inv_cnt;
  float s2 = gstats[b * 8 + 4 + g] * inv_cnt;
  float rs = rsqrtf(s2 - m * m + 1e-5f);
  float sc = gw[o] * rs;
  float sel = (sc >= 0.f) ? ymax[i] : ymin[i];
  float v = (sel - m) * sc + gb[o];
  fout[i] = (v > 0.f) ? v : 0.2f * v;
}

// ---------------------------------------------------------------------------
extern "C" void kernel_launch(void* const* d_in, const int* in_sizes, int n_in,
                              void* d_out, int out_size, void* d_ws, size_t ws_size,
                              hipStream_t stream) {
  (void)in_sizes; (void)n_in; (void)out_size; (void)ws_size;
  const float* x    = (const float*)d_in[0];
  const float* W_in = (const float*)d_in[1];
  const float* b_in = (const float*)d_in[2];
  const float* W1   = (const float*)d_in[3];
  const float* g1w  = (const float*)d_in[4];
  const float* g1b  = (const float*)d_in[5];
  const float* W2   = (const float*)d_in[6];
  const float* g2w  = (const float*)d_in[7];
  const float* g2b  = (const float*)d_in[8];
  const float* W3   = (const float*)d_in[9];
  const float* g3w  = (const float*)d_in[10];
  const float* g3b  = (const float*)d_in[11];
  const float* W4   = (const float*)d_in[12];
  const float* g4w  = (const float*)d_in[13];
  const float* g4b  = (const float*)d_in[14];

  float* ws = (float*)d_ws;
  size_t o_c40  = 0;                                         // float4-aligned
  size_t o_nrm  = o_c40  + (size_t)B * N0 * 4;
  size_t o_pl   = o_nrm  + (size_t)B * N0 * 3;
  size_t o_f0   = o_pl   + (size_t)B * N0;
  size_t o_f1   = o_f0   + (size_t)B * N0 * 8;
  size_t o_ctrY = o_f1   + (size_t)B * N0 * 32;
  size_t o_ymin = o_ctrY + (size_t)B * N0 * 32;
  size_t o_ymax = o_ymin + (size_t)B * N0 * 32;
  size_t o_knnA = o_ymax + (size_t)B * N0 * 32;              // int region
  size_t o_knnB = o_knnA + (size_t)B * N0 * KNB;             // int region
  size_t o_gst  = o_knnB + (size_t)B * NQ * KNB;
  size_t o_idx1 = o_gst  + 4 * B * 8;                        // int region
  size_t o_idx2 = o_idx1 + (size_t)B * NQ;                   // int region
  size_t o_c4q1 = o_idx2 + (size_t)B * NQ;                   // float4-aligned
  size_t o_c4q2 = o_c4q1 + (size_t)B * NQ * 4;               // float4-aligned
  size_t o_nq1  = o_c4q2 + (size_t)B * NQ * 4;
  size_t o_pq1  = o_nq1  + (size_t)B * NQ * 3;
  size_t o_f2   = o_pq1  + (size_t)B * NQ;
  size_t o_f3   = o_f2   + (size_t)B * NQ * 64;
  size_t o_knnC = o_f3   + (size_t)B * NQ * 64;              // int region (new)

  float4* c40  = (float4*)(ws + o_c40);
  float*  nrm  = ws + o_nrm;   float* pl   = ws + o_pl;
  float*  f0   = ws + o_f0;    float* f1   = ws + o_f1;
  float*  ctrY = ws + o_ctrY;  float* ymin = ws + o_ymin;  float* ymax = ws + o_ymax;
  int*    knnA = (int*)(ws + o_knnA);
  int*    knnB = (int*)(ws + o_knnB);
  int*    knnC = (int*)(ws + o_knnC);
  float*  gst  = ws + o_gst;
  int*    idx1 = (int*)(ws + o_idx1);
  int*    idx2 = (int*)(ws + o_idx2);
  float4* c4q1 = (float4*)(ws + o_c4q1);
  float4* c4q2 = (float4*)(ws + o_c4q2);
  float*  nq1  = ws + o_nq1;   float* pq1  = ws + o_pq1;
  float*  f2   = ws + o_f2;    float* f3   = ws + o_f3;

  float* out  = (float*)d_out;
  float* cq2  = out;                                   // (B,NQ,3)
  float* fout = out + (size_t)B * NQ * 3;              // (B,NQ,128)
  float* nq2  = fout + (size_t)B * NQ * 128;           // (B,NQ,3)
  float* pq2  = nq2 + (size_t)B * NQ * 3;              // (B,NQ,1)

  hipMemsetAsync(gst, 0, 4 * B * 8 * sizeof(float), stream);

  // stage 0
  prep_kernel<<<(B * N0 + 255) / 256, 256, 0, stream>>>(x, W_in, b_in, c40, nrm, pl, f0);

  // mega1: fps1 || knn1 || ctry1   (deps: prep only)
  mega1_kernel<<<8 + 8192 + 4096, 256, 0, stream>>>(c40, nrm, pl, f0, W1,
                                                    idx1, c4q1, nq1, pq1, knnA, ctrY);
  // ec1f: fps2 (1-wave v10) || edgeconv1 || knn2 || knn3   (deps: mega1 only)
  ec1f_kernel<<<8 + 8192 + 2048 + 2048, 256, 0, stream>>>(
      c40, c4q1, nq1, pq1, f0, knnA, W1, ctrY, ymin, ymax, gst + 0,
      idx2, c4q2, cq2, nq2, pq2, knnC, knnB);
  gn_out_kernel<32><<<(B * N0 * 32 + 255) / 256, 256, 0, stream>>>(
      ymin, ymax, gst + 0, g1w, g1b, f1, B * N0 * 32, N0, 1.0f / (4096.0f * 16.0f * 8.0f));

  // layer 2: ctrY then edgeconv (knn2 already computed in ec1f -> knnC)
  ctry_kernel<32, 64><<<(B * NQ * 64 + 255) / 256, 256, 0, stream>>>(
      f1, W2, ctrY, B * NQ * 64, idx1, NQ, N0);
  edgeconv_kernel<32, 64><<<B * NQ / 4, 256, 0, stream>>>(f1, f1, knnC, W2, ctrY, idx1,
                                                          ymin, ymax, gst + B * 8, NQ, N0);
  gn_out_kernel<64><<<(B * NQ * 64 + 255) / 256, 256, 0, stream>>>(
      ymin, ymax, gst + B * 8, g2w, g2b, f2, B * NQ * 64, NQ, 1.0f / (1024.0f * 16.0f * 16.0f));

  // layer 3 (dense; knn3 already computed in ec1f -> knnB)
  ctry_kernel<64, 64><<<(B * NQ * 64 + 255) / 256, 256, 0, stream>>>(
      f2, W3, ctrY, B * NQ * 64, nullptr, 0, 0);
  edgeconv_kernel<64, 64><<<B * NQ / 4, 256, 0, stream>>>(f2, f2, knnB, W3, ctrY, nullptr,
                                                          ymin, ymax, gst + 2 * B * 8, NQ, NQ);
  gn_out_kernel<64><<<(B * NQ * 64 + 255) / 256, 256, 0, stream>>>(
      ymin, ymax, gst + 2 * B * 8, g3w, g3b, f3, B * NQ * 64, NQ, 1.0f / (1024.0f * 16.0f * 16.0f));

  // mega3: knn4 || ctry4   (deps: ec1f + gn_out3)
  mega3_kernel<<<2048 + 4096, 256, 0, stream>>>(c4q1, c4q2, f3, idx2, W4, knnB, ctrY);
  // layer 4 finish
  edgeconv_kernel<64, 128><<<B * NQ / 4, 256, 0, stream>>>(f3, f3, knnB, W4, ctrY, idx2,
                                                           ymin, ymax, gst + 3 * B * 8, NQ, NQ);
  gn_out_kernel<128><<<(B * NQ * 128 + 255) / 256, 256, 0, stream>>>(
      ymin, ymax, gst + 3 * B * 8, g4w, g4b, fout, B * NQ * 128, NQ, 1.0f / (1024.0f * 16.0f * 32.0f));
}

// Round 7
// 1449.593 us; speedup vs baseline: 1.2484x; 1.2484x over previous
//
#include <hip/hip_runtime.h>
#include <cstdint>

static constexpr int B   = 8;
static constexpr int N0  = 4096;
static constexpr int NQ  = 1024;
static constexpr int KNB = 16;

// ---------------------------------------------------------------------------
// u64 wave max; result valid in LANE 63 only. No readlane/ballot — pure VALU.
// ---------------------------------------------------------------------------
__device__ __forceinline__ unsigned long long wave_max_u64_l63(unsigned long long k) {
#define STEPU_(ctrl)                                                                    \
  {                                                                                     \
    unsigned lo_ = (unsigned)k, hi_ = (unsigned)(k >> 32);                              \
    unsigned plo_ = (unsigned)__builtin_amdgcn_update_dpp((int)lo_, (int)lo_, ctrl,     \
                                                          0xf, 0xf, false);             \
    unsigned phi_ = (unsigned)__builtin_amdgcn_update_dpp((int)hi_, (int)hi_, ctrl,     \
                                                          0xf, 0xf, false);             \
    unsigned long long pk_ = ((unsigned long long)phi_ << 32) | plo_;                   \
    if (pk_ > k) k = pk_;                                                               \
  }
  STEPU_(0x111) STEPU_(0x112) STEPU_(0x114) STEPU_(0x118) STEPU_(0x142) STEPU_(0x143)
#undef STEPU_
  return k;
}

// ---------------------------------------------------------------------------
// prep: split x; write packed c4 = {x,y,z,|c|^2}, normal, plane, f0
// ---------------------------------------------------------------------------
__global__ void prep_kernel(const float* __restrict__ x,
                            const float* __restrict__ W_in,
                            const float* __restrict__ b_in,
                            float4* __restrict__ c4, float* __restrict__ nrm,
                            float* __restrict__ pl, float* __restrict__ f0) {
  int i = blockIdx.x * 256 + threadIdx.x;
  if (i >= B * N0) return;
  const float* xp = x + (size_t)i * 7;
  float cx = xp[0], cy = xp[1], cz = xp[2];
  // tie-sensitive (feeds kNN distance): exact fp32, ref association order
  float kk = __fadd_rn(__fadd_rn(__fmul_rn(cx, cx), __fmul_rn(cy, cy)), __fmul_rn(cz, cz));
  c4[i] = make_float4(cx, cy, cz, kk);
  nrm[i * 3 + 0] = xp[3]; nrm[i * 3 + 1] = xp[4]; nrm[i * 3 + 2] = xp[5];
  pl[i] = xp[6];
#pragma unroll
  for (int o = 0; o < 8; o++) {
    f0[(size_t)i * 8 + o] = cx * W_in[o * 3 + 0] + cy * W_in[o * 3 + 1] + cz * W_in[o * 3 + 2] + b_in[o];
  }
}

// ---------------------------------------------------------------------------
// kNN body: STREAMING INSERTION TOP-K (harness-verified R1). Wave per query.
// ---------------------------------------------------------------------------
template <int NC>
__device__ __forceinline__ void knn_body(int bq, int lane,
                                         const float4* __restrict__ q4,
                                         const float4* __restrict__ k4,
                                         int Q, int Nk, int* __restrict__ out) {
  int b = bq / Q;
  float4 q = q4[bq];
  const float4* kb = k4 + (size_t)b * Nk + lane;
  const float INF    = __int_as_float(0x7f800000);
  const float NEGINF = __int_as_float(0xff800000);
  float myd = INF;  // sorted list value (replicated per 16-lane row)
  int   myi = 0;
  float kth = INF;  // current 16th-smallest (wave-uniform scalar)
  const bool isl0 = (lane & 15) == 0;
  constexpr int G = (NC >= 8) ? 8 : NC;  // load-batching group
  for (int c0 = 0; c0 < NC; c0 += G) {
    float dg[G];
#pragma unroll
    for (int u = 0; u < G; u++) {
      float4 kp = kb[(c0 + u) * 64];
      float dot = __fadd_rn(__fadd_rn(__fmul_rn(q.x, kp.x), __fmul_rn(q.y, kp.y)),
                            __fmul_rn(q.z, kp.z));
      dg[u] = __fadd_rn(__fsub_rn(q.w, __fmul_rn(2.0f, dot)), kp.w);
    }
#pragma unroll
    for (int u = 0; u < G; u++) {
      float d = dg[u];
      unsigned long long m = __ballot(d < kth);
      while (m) {
        int j = __builtin_ctzll(m);  // wave-uniform (scalar)
        float dv = __int_as_float(__builtin_amdgcn_readlane(__float_as_int(d), j));
        int   iv = (c0 + u) * 64 + j;
        // insert (dv, iv): shift-down all positions with value > dv
        bool gt = (myd > dv);
        float pd = __int_as_float(__builtin_amdgcn_update_dpp(
            0, __float_as_int(myd), 0x111, 0xf, 0xf, true));
        int   pi = __builtin_amdgcn_update_dpp(0, myi, 0x111, 0xf, 0xf, true);
        pd = isl0 ? NEGINF : pd;  // position 0 always takes dv when it shifts
        bool tp = (pd > dv);
        float nd = tp ? pd : dv;
        int   ni = tp ? pi : iv;
        myd = gt ? nd : myd;
        myi = gt ? ni : myi;
        kth = __int_as_float(__builtin_amdgcn_readlane(__float_as_int(myd), 15));
        m = __ballot(d < kth);  // kth only shrinks -> lanes may drop out
        m = (j < 63) ? (m & (~0ull << (j + 1))) : 0ull;  // only lanes > j remain
      }
    }
  }
  if (lane < KNB) out[(size_t)bq * KNB + lane] = myi;
}

// ---------------------------------------------------------------------------
// ctrY body: ctrY[b,q,o] = sum_c fq_row[c] * W[o, CF+c]; optional ridx.
// ---------------------------------------------------------------------------
template <int CF, int CO>
__device__ __forceinline__ void ctry_body(int i, int total, const float* __restrict__ fq,
                                          const float* __restrict__ W,
                                          float* __restrict__ ctrY,
                                          const int* __restrict__ ridx, int Q, int Nsrc) {
  if (i >= total) return;
  int o = i % CO, bq = i / CO;
  const float* fp;
  if (ridx) {
    int b = bq / Q;
    fp = fq + ((size_t)b * Nsrc + ridx[bq]) * CF;
  } else {
    fp = fq + (size_t)bq * CF;
  }
  const float* wp = W + (size_t)o * (2 * CF) + CF;
  float acc = 0.f;
#pragma unroll
  for (int c = 0; c < CF; c++) acc = fmaf(fp[c], wp[c], acc);
  ctrY[i] = acc;
}

// ---------------------------------------------------------------------------
// FPS v5 (harness-verified R1): BLK=256 (4 waves), one block per batch.
// key k=(dist_bits<<12)|(4095-bi) DPP-u64-maxed; lane 63 writes wave slot;
// ONE barrier; cross-wave reduce = 2x ds_read_b128 broadcast + 3 u64 maxes;
// winner coords via same-address (broadcast) LDS reads sxy[win]/sz[win].
// u64 max == (max dist, tie -> min index) == jnp.argmax first-occurrence.
// ---------------------------------------------------------------------------
template <int NPTS>
__device__ __forceinline__ void fps_body(const float4* __restrict__ cb, int* w) {
  constexpr int BLK = 256;
  constexpr int M = NPTS / BLK;
  constexpr int NW = BLK / 64;  // 4
  __shared__ __align__(16) float2 sxy[NPTS];
  __shared__ float szz[NPTS];
  __shared__ __align__(16) unsigned long long skey[2][NW];
  const int tid = threadIdx.x;
  const int wid = tid >> 6, lane = tid & 63;
  float cx[M], cy[M], cz[M], dist[M];
#pragma unroll
  for (int i = 0; i < M; i++) {
    float4 p = cb[tid * M + i];
    cx[i] = p.x; cy[i] = p.y; cz[i] = p.z;
    dist[i] = 3.4e38f;
    sxy[tid * M + i] = make_float2(p.x, p.y);
    szz[tid * M + i] = p.z;
  }
  w[0] = w[1] = w[2] = w[3] = 0;
  float4 p0 = cb[0];
  float px = p0.x, py = p0.y, pz = p0.z;
  __syncthreads();
  for (int t = 1; t < NQ; t++) {
    float bv = -1.f; int bi = 0;
#pragma unroll
    for (int i = 0; i < M; i++) {
      float dx = __fsub_rn(cx[i], px), dy = __fsub_rn(cy[i], py), dz = __fsub_rn(cz[i], pz);
      float d = __fadd_rn(__fadd_rn(__fmul_rn(dx, dx), __fmul_rn(dy, dy)), __fmul_rn(dz, dz));
      float dd = dist[i]; dd = (d < dd) ? d : dd; dist[i] = dd;
      if (dd > bv) { bv = dd; bi = tid * M + i; }
    }
    unsigned long long k =
        ((unsigned long long)__float_as_uint(bv) << 12) | (unsigned)(4095 - bi);
    k = wave_max_u64_l63(k);
    int p = t & 1;
    if (lane == 63) skey[p][wid] = k;
    __syncthreads();
    ulonglong2 ab = *(const ulonglong2*)&skey[p][0];
    ulonglong2 cd = *(const ulonglong2*)&skey[p][2];
    unsigned long long m0 = (ab.x > ab.y) ? ab.x : ab.y;
    unsigned long long m1 = (cd.x > cd.y) ? cd.x : cd.y;
    unsigned long long mk = (m0 > m1) ? m0 : m1;
    int win = 4095 - (int)(mk & 0xFFFull);
    float2 pxy = sxy[win];
    px = pxy.x; py = pxy.y; pz = szz[win];
    if (t == tid) w[0] = win;
    if (t == tid + 256) w[1] = win;
    if (t == tid + 512) w[2] = win;
    if (t == tid + 768) w[3] = win;
  }
}

// ---------------------------------------------------------------------------
// edge-conv pass A body (NT threads): wave per (b,q); lane = g*16+k.
// ---------------------------------------------------------------------------
template <int CF, int CO, int NT>
__device__ __forceinline__ void edgeconv_body(
    int blkid, const float* __restrict__ fq, const float* __restrict__ fk,
    const int* __restrict__ knn, const float* __restrict__ Wfull,
    const float* __restrict__ ctrY, const int* __restrict__ ridx,
    float* __restrict__ ymin, float* __restrict__ ymax,
    float* __restrict__ gstats, int Q, int Nk) {
  constexpr int J = CO / 4;
  constexpr int SEC = J * CF + 8;
  constexpr int NWARP = NT / 64;
  __shared__ float Wl[4 * SEC];
  __shared__ float sstat[8];
  for (int t = threadIdx.x; t < CO * CF; t += NT) {
    int o = t / CF, c = t % CF;
    Wl[(o / J) * SEC + (o % J) * CF + c] = Wfull[(size_t)o * (2 * CF) + c];
  }
  if (threadIdx.x < 8) sstat[threadIdx.x] = 0.0f;
  __syncthreads();
  const int wid = threadIdx.x >> 6, lane = threadIdx.x & 63;
  const int bq = blkid * NWARP + wid;
  const int b = bq / Q;
  const int g = lane >> 4, k = lane & 15;
  const int ni = knn[(size_t)bq * KNB + k];
  const float* nbp = fk + (size_t)(b * Nk + ni) * CF;
  const float* cp = ridx ? fq + ((size_t)b * Nk + ridx[bq]) * CF
                         : fq + (size_t)bq * CF;
  float acc[J];
#pragma unroll
  for (int j = 0; j < J; j++) acc[j] = 0.0f;
  const float* wg = &Wl[g * SEC];
#pragma unroll
  for (int c = 0; c < CF; c += 4) {
    float4 nb4 = *(const float4*)(nbp + c);
    float4 c4  = *(const float4*)(cp + c);
    float e0 = nb4.x - c4.x, e1 = nb4.y - c4.y, e2 = nb4.z - c4.z, e3 = nb4.w - c4.w;
#pragma unroll
    for (int j = 0; j < J; j++) {
      float4 w4 = *(const float4*)(wg + j * CF + c);
      acc[j] = fmaf(e0, w4.x, acc[j]);
      acc[j] = fmaf(e1, w4.y, acc[j]);
      acc[j] = fmaf(e2, w4.z, acc[j]);
      acc[j] = fmaf(e3, w4.w, acc[j]);
    }
  }
  float s = 0.f, s2 = 0.f;
  const float* cyp = ctrY + (size_t)bq * CO + g * J;
#pragma unroll
  for (int j = 0; j < J; j++) {
    float y = acc[j] + cyp[j];
    acc[j] = y;            // acc becomes running max
    s += y; s2 = fmaf(y, y, s2);
  }
  float mn[J];
#pragma unroll
  for (int j = 0; j < J; j++) mn[j] = acc[j];
#pragma unroll
  for (int m = 1; m < 16; m <<= 1) {  // reduce over the 16 k-lanes
#pragma unroll
    for (int j = 0; j < J; j++) {
      float a = __shfl_xor(acc[j], m); if (a > acc[j]) acc[j] = a;
      float c2 = __shfl_xor(mn[j], m); if (c2 < mn[j]) mn[j] = c2;
    }
    s  += __shfl_xor(s, m);
    s2 += __shfl_xor(s2, m);
  }
  if (k == 0) {
    float* mnp = ymin + (size_t)bq * CO + g * J;
    float* mxp = ymax + (size_t)bq * CO + g * J;
#pragma unroll
    for (int j = 0; j < J; j++) { mnp[j] = mn[j]; mxp[j] = acc[j]; }
    atomicAdd(&sstat[g], s);
    atomicAdd(&sstat[4 + g], s2);
  }
  __syncthreads();
  if (threadIdx.x < 8) atomicAdd(&gstats[b * 8 + threadIdx.x], sstat[threadIdx.x]);
}

// ---------------------------------------------------------------------------
// mega1 (256 thr): blocks [0,8) fps1 v5 (+ gather tail); [8,8+8192) knn1;
// rest ctry1. All roles depend only on prep outputs. (R1-proven, unchanged.)
// ---------------------------------------------------------------------------
__global__ __launch_bounds__(256, 2) void mega1_kernel(
    const float4* __restrict__ c40, const float* __restrict__ nrm,
    const float* __restrict__ pl, const float* __restrict__ f0,
    const float* __restrict__ W1, int* __restrict__ idx1,
    float4* __restrict__ c4q1, float* __restrict__ nq1, float* __restrict__ pq1,
    int* __restrict__ knn1, float* __restrict__ ctrY1) {
  int blk = blockIdx.x;
  if (blk < 8) {
    const int b = blk, tid = threadIdx.x;
    const float4* cb = c40 + (size_t)b * N0;
    int w[4];
    fps_body<N0>(cb, w);
    int* idxb = idx1 + (size_t)b * NQ;
#pragma unroll
    for (int u = 0; u < 4; u++) {
      int r = tid + u * 256;
      int s = (u == 0 && tid == 0) ? 0 : w[u];
      idxb[r] = s;
      c4q1[(size_t)b * NQ + r] = cb[s];
      const float* np = nrm + ((size_t)b * N0 + s) * 3;
      float* ndp = nq1 + ((size_t)b * NQ + r) * 3;
      ndp[0] = np[0]; ndp[1] = np[1]; ndp[2] = np[2];
      pq1[(size_t)b * NQ + r] = pl[(size_t)b * N0 + s];
    }
  } else if (blk < 8 + 8192) {
    int bq = (blk - 8) * 4 + (threadIdx.x >> 6);
    knn_body<64>(bq, threadIdx.x & 63, c40, c40, N0, N0, knn1);
  } else {
    int i = (blk - (8 + 8192)) * 256 + threadIdx.x;
    ctry_body<8, 32>(i, B * N0 * 32, f0, W1, ctrY1, nullptr, 0, 0);
  }
}

// ---------------------------------------------------------------------------
// mega2 (256 thr): blocks [0,8) fps2 v5 4-wave (+ gather tail -> idx2, c4q2,
// d_out coords/normal/plane); [8,8+8192) edgeconv layer 1 (hides under the
// fps2 serial tail); [.., +2048) knn2 -> knnC (fresh buffer: knnA is still
// being read by the ec1 role); [.., +2048) knn3 -> knnB.
// All roles depend only on mega1 outputs. ctry2 moved out (needs gn1's f1).
// ---------------------------------------------------------------------------
__global__ __launch_bounds__(256, 2) void mega2_kernel(
    const float4* __restrict__ c40, const float4* __restrict__ c4q1,
    const float* __restrict__ nq1, const float* __restrict__ pq1,
    const float* __restrict__ f0, const int* __restrict__ knn1,
    const float* __restrict__ W1, const float* __restrict__ ctrY1,
    float* __restrict__ ymin, float* __restrict__ ymax, float* __restrict__ gst1,
    int* __restrict__ idx2, float4* __restrict__ c4q2,
    float* __restrict__ cq2out, float* __restrict__ nq2out,
    float* __restrict__ pq2out, int* __restrict__ knnC, int* __restrict__ knnB) {
  int blk = blockIdx.x;
  if (blk < 8) {
    const int b = blk, tid = threadIdx.x;
    const float4* cqb = c4q1 + (size_t)b * NQ;
    int w[4];
    fps_body<NQ>(cqb, w);
    int* idxb = idx2 + (size_t)b * NQ;
#pragma unroll
    for (int u = 0; u < 4; u++) {
      int r = tid + u * 256;
      int s = (u == 0 && tid == 0) ? 0 : w[u];
      idxb[r] = s;
      float4 c = cqb[s];
      c4q2[(size_t)b * NQ + r] = c;
      float* cd = cq2out + ((size_t)b * NQ + r) * 3;
      cd[0] = c.x; cd[1] = c.y; cd[2] = c.z;
      const float* np = nq1 + ((size_t)b * NQ + s) * 3;
      float* ndp = nq2out + ((size_t)b * NQ + r) * 3;
      ndp[0] = np[0]; ndp[1] = np[1]; ndp[2] = np[2];
      pq2out[(size_t)b * NQ + r] = pq1[(size_t)b * NQ + s];
    }
  } else if (blk < 8 + 8192) {
    edgeconv_body<8, 32, 256>(blk - 8, f0, f0, knn1, W1, ctrY1, nullptr,
                              ymin, ymax, gst1, N0, N0);
  } else if (blk < 8 + 8192 + 2048) {
    int bq = (blk - (8 + 8192)) * 4 + (threadIdx.x >> 6);
    knn_body<64>(bq, threadIdx.x & 63, c4q1, c40, NQ, N0, knnC);
  } else {
    int bq = (blk - (8 + 8192 + 2048)) * 4 + (threadIdx.x >> 6);
    knn_body<16>(bq, threadIdx.x & 63, c4q1, c4q1, NQ, NQ, knnB);
  }
}

// ---------------------------------------------------------------------------
// mega3 (256 thr): [0,2048) knn4 (c4q2 vs c4q1) -> knnB (knn3 consumed by
// ec3 already); rest ctry4 (f3 rows via idx2).
// ---------------------------------------------------------------------------
__global__ __launch_bounds__(256, 4) void mega3_kernel(
    const float4* __restrict__ c4q1, const float4* __restrict__ c4q2,
    const float* __restrict__ f3, const int* __restrict__ idx2,
    const float* __restrict__ W4, int* __restrict__ knn4, float* __restrict__ ctrY4) {
  int blk = blockIdx.x;
  if (blk < 2048) {
    int bq = blk * 4 + (threadIdx.x >> 6);
    knn_body<16>(bq, threadIdx.x & 63, c4q2, c4q1, NQ, NQ, knn4);
  } else {
    int i = (blk - 2048) * 256 + threadIdx.x;
    ctry_body<64, 128>(i, B * NQ * 128, f3, W4, ctrY4, idx2, NQ, NQ);
  }
}

// ---------------------------------------------------------------------------
// standalone ctry (layers 2 & 3; optional ridx)
// ---------------------------------------------------------------------------
template <int CF, int CO>
__global__ void ctry_kernel(const float* __restrict__ fq, const float* __restrict__ W,
                            float* __restrict__ ctrY, int total,
                            const int* __restrict__ ridx, int Q, int Nsrc) {
  int i = blockIdx.x * 256 + threadIdx.x;
  ctry_body<CF, CO>(i, total, fq, W, ctrY, ridx, Q, Nsrc);
}

// ---------------------------------------------------------------------------
// standalone edgeconv (layers 2,3,4) — 256 thr
// ---------------------------------------------------------------------------
template <int CF, int CO>
__global__ __launch_bounds__(256) void edgeconv_kernel(
    const float* __restrict__ fq, const float* __restrict__ fk,
    const int* __restrict__ knn, const float* __restrict__ Wfull,
    const float* __restrict__ ctrY, const int* __restrict__ ridx,
    float* __restrict__ ymin, float* __restrict__ ymax,
    float* __restrict__ gstats, int Q, int Nk) {
  edgeconv_body<CF, CO, 256>(blockIdx.x, fq, fk, knn, Wfull, ctrY, ridx,
                             ymin, ymax, gstats, Q, Nk);
}

// ---------------------------------------------------------------------------
// pass B (gn_final fused): f = lrelu((sel - m)*gw*rs + gb),
// sel = max over K if scale>=0 else min (monotone-commute, exact).
// ---------------------------------------------------------------------------
template <int CO>
__global__ void gn_out_kernel(const float* __restrict__ ymin, const float* __restrict__ ymax,
                              const float* __restrict__ gstats, const float* __restrict__ gw,
                              const float* __restrict__ gb, float* __restrict__ fout,
                              int total, int Q, float inv_cnt) {
  int i = blockIdx.x * 256 + threadIdx.x;
  if (i >= total) return;
  constexpr int J = CO / 4;
  int o = i % CO; int bq = i / CO; int b = bq / Q;
  int g = o / J;
  float m  = gstats[b * 8 + g] * inv_cnt;
  float s2 = gstats[b * 8 + 4 + g] * inv_cnt;
  float rs = rsqrtf(s2 - m * m + 1e-5f);
  float sc = gw[o] * rs;
  float sel = (sc >= 0.f) ? ymax[i] : ymin[i];
  float v = (sel - m) * sc + gb[o];
  fout[i] = (v > 0.f) ? v : 0.2f * v;
}

// ---------------------------------------------------------------------------
extern "C" void kernel_launch(void* const* d_in, const int* in_sizes, int n_in,
                              void* d_out, int out_size, void* d_ws, size_t ws_size,
                              hipStream_t stream) {
  (void)in_sizes; (void)n_in; (void)out_size; (void)ws_size;
  const float* x    = (const float*)d_in[0];
  const float* W_in = (const float*)d_in[1];
  const float* b_in = (const float*)d_in[2];
  const float* W1   = (const float*)d_in[3];
  const float* g1w  = (const float*)d_in[4];
  const float* g1b  = (const float*)d_in[5];
  const float* W2   = (const float*)d_in[6];
  const float* g2w  = (const float*)d_in[7];
  const float* g2b  = (const float*)d_in[8];
  const float* W3   = (const float*)d_in[9];
  const float* g3w  = (const float*)d_in[10];
  const float* g3b  = (const float*)d_in[11];
  const float* W4   = (const float*)d_in[12];
  const float* g4w  = (const float*)d_in[13];
  const float* g4b  = (const float*)d_in[14];

  float* ws = (float*)d_ws;
  size_t o_c40  = 0;                                         // float4-aligned
  size_t o_nrm  = o_c40  + (size_t)B * N0 * 4;
  size_t o_pl   = o_nrm  + (size_t)B * N0 * 3;
  size_t o_f0   = o_pl   + (size_t)B * N0;
  size_t o_f1   = o_f0   + (size_t)B * N0 * 8;
  size_t o_ctrY = o_f1   + (size_t)B * N0 * 32;
  size_t o_ymin = o_ctrY + (size_t)B * N0 * 32;
  size_t o_ymax = o_ymin + (size_t)B * N0 * 32;
  size_t o_knnA = o_ymax + (size_t)B * N0 * 32;              // int region
  size_t o_knnB = o_knnA + (size_t)B * N0 * KNB;             // int region
  size_t o_gst  = o_knnB + (size_t)B * NQ * KNB;
  size_t o_idx1 = o_gst  + 4 * B * 8;                        // int region
  size_t o_idx2 = o_idx1 + (size_t)B * NQ;                   // int region
  size_t o_c4q1 = o_idx2 + (size_t)B * NQ;                   // float4-aligned
  size_t o_c4q2 = o_c4q1 + (size_t)B * NQ * 4;               // float4-aligned
  size_t o_nq1  = o_c4q2 + (size_t)B * NQ * 4;
  size_t o_pq1  = o_nq1  + (size_t)B * NQ * 3;
  size_t o_f2   = o_pq1  + (size_t)B * NQ;
  size_t o_f3   = o_f2   + (size_t)B * NQ * 64;
  size_t o_knnC = o_f3   + (size_t)B * NQ * 64;              // int region

  float4* c40  = (float4*)(ws + o_c40);
  float*  nrm  = ws + o_nrm;   float* pl   = ws + o_pl;
  float*  f0   = ws + o_f0;    float* f1   = ws + o_f1;
  float*  ctrY = ws + o_ctrY;  float* ymin = ws + o_ymin;  float* ymax = ws + o_ymax;
  int*    knnA = (int*)(ws + o_knnA);
  int*    knnB = (int*)(ws + o_knnB);
  int*    knnC = (int*)(ws + o_knnC);
  float*  gst  = ws + o_gst;
  int*    idx1 = (int*)(ws + o_idx1);
  int*    idx2 = (int*)(ws + o_idx2);
  float4* c4q1 = (float4*)(ws + o_c4q1);
  float4* c4q2 = (float4*)(ws + o_c4q2);
  float*  nq1  = ws + o_nq1;   float* pq1  = ws + o_pq1;
  float*  f2   = ws + o_f2;    float* f3   = ws + o_f3;

  float* out  = (float*)d_out;
  float* cq2  = out;                                   // (B,NQ,3)
  float* fout = out + (size_t)B * NQ * 3;              // (B,NQ,128)
  float* nq2  = fout + (size_t)B * NQ * 128;           // (B,NQ,3)
  float* pq2  = nq2 + (size_t)B * NQ * 3;              // (B,NQ,1)

  hipMemsetAsync(gst, 0, 4 * B * 8 * sizeof(float), stream);

  // stage 0
  prep_kernel<<<(B * N0 + 255) / 256, 256, 0, stream>>>(x, W_in, b_in, c40, nrm, pl, f0);

  // mega1: fps1 || knn1 || ctry1   (deps: prep only)
  mega1_kernel<<<8 + 8192 + 4096, 256, 0, stream>>>(c40, nrm, pl, f0, W1,
                                                    idx1, c4q1, nq1, pq1, knnA, ctrY);
  // mega2: fps2 || edgeconv1 || knn2 || knn3   (deps: mega1 only;
  // ec1 hides under the fps2 serial tail)
  mega2_kernel<<<8 + 8192 + 2048 + 2048, 256, 0, stream>>>(
      c40, c4q1, nq1, pq1, f0, knnA, W1, ctrY, ymin, ymax, gst + 0,
      idx2, c4q2, cq2, nq2, pq2, knnC, knnB);
  gn_out_kernel<32><<<(B * N0 * 32 + 255) / 256, 256, 0, stream>>>(
      ymin, ymax, gst + 0, g1w, g1b, f1, B * N0 * 32, N0, 1.0f / (4096.0f * 16.0f * 8.0f));

  // layer 2 (knn2 already computed in mega2 -> knnC)
  ctry_kernel<32, 64><<<(B * NQ * 64 + 255) / 256, 256, 0, stream>>>(
      f1, W2, ctrY, B * NQ * 64, idx1, NQ, N0);
  edgeconv_kernel<32, 64><<<B * NQ / 4, 256, 0, stream>>>(f1, f1, knnC, W2, ctrY, idx1,
                                                          ymin, ymax, gst + B * 8, NQ, N0);
  gn_out_kernel<64><<<(B * NQ * 64 + 255) / 256, 256, 0, stream>>>(
      ymin, ymax, gst + B * 8, g2w, g2b, f2, B * NQ * 64, NQ, 1.0f / (1024.0f * 16.0f * 16.0f));

  // layer 3 (dense; knn3 already computed in mega2 -> knnB)
  ctry_kernel<64, 64><<<(B * NQ * 64 + 255) / 256, 256, 0, stream>>>(
      f2, W3, ctrY, B * NQ * 64, nullptr, 0, 0);
  edgeconv_kernel<64, 64><<<B * NQ / 4, 256, 0, stream>>>(f2, f2, knnB, W3, ctrY, nullptr,
                                                          ymin, ymax, gst + 2 * B * 8, NQ, NQ);
  gn_out_kernel<64><<<(B * NQ * 64 + 255) / 256, 256, 0, stream>>>(
      ymin, ymax, gst + 2 * B * 8, g3w, g3b, f3, B * NQ * 64, NQ, 1.0f / (1024.0f * 16.0f * 16.0f));

  // mega3: knn4 || ctry4   (deps: mega2 + gn_out3)
  mega3_kernel<<<2048 + 4096, 256, 0, stream>>>(c4q1, c4q2, f3, idx2, W4, knnB, ctrY);
  // layer 4 finish
  edgeconv_kernel<64, 128><<<B * NQ / 4, 256, 0, stream>>>(f3, f3, knnB, W4, ctrY, idx2,
                                                           ymin, ymax, gst + 3 * B * 8, NQ, NQ);
  gn_out_kernel<128><<<(B * NQ * 128 + 255) / 256, 256, 0, stream>>>(
      ymin, ymax, gst + 3 * B * 8, g4w, g4b, fout, B * NQ * 128, NQ, 1.0f / (1024.0f * 16.0f * 32.0f));
}